// Round 7
// baseline (366.365 us; speedup 1.0000x reference)
//
#include <hip/hip_runtime.h>
#include <hip/hip_bf16.h>

#define DD 128
#define D3 (DD*DD*DD)      // 2097152
#define NB 8               // batch
#define NV 65536           // points
#define HID 256
#define LAT 128

// bricks: 32x8x4 voxels -> 4 x 16 x 32 = 2048 per batch, 16384 total
#define NBIN 2048
#define NBIN_TOT (NBIN*NB) // 16384

// round-to-nearest-even f32 -> bf16, returned as the (exactly representable) f32 value
__device__ __forceinline__ float rbf(float x) {
    unsigned u = __float_as_uint(x);
    unsigned r = (u + 0x7fffu + ((u >> 16) & 1u)) & 0xFFFF0000u;
    return __uint_as_float(r);
}

// ---------------- SIREN layer: one kernel per layer, 4 blocks x 256 threads --------
template<int K, int MODE>
__global__ __launch_bounds__(256) void k_layer(
    const float* __restrict__ in, const float* __restrict__ w,
    const float* __restrict__ bias, float* __restrict__ outp)
{
    __shared__ float in_s[NB * K];
    __shared__ float part[4 * 64 * 8];    // 8 KB
    const int tid = threadIdx.x;
    for (int i = tid; i < NB * K; i += 256) in_s[i] = rbf(in[i]);
    __syncthreads();

    const int cl = tid & 63;             // column within block (wave-contiguous)
    const int ks = tid >> 6;             // k-slice 0..3 (wave-uniform)
    const int col = blockIdx.x * 64 + cl;

    float acc[NB];
    #pragma unroll
    for (int b = 0; b < NB; ++b) acc[b] = 0.f;

    const int k0 = ks * (K / 4);
    #pragma unroll 8
    for (int k = k0; k < k0 + K / 4; ++k) {
        float wk = rbf(w[k * HID + col]);          // 256B/wave coalesced
        #pragma unroll
        for (int b = 0; b < NB; ++b) acc[b] = fmaf(in_s[b * K + k], wk, acc[b]);
    }

    float* pp = part + (ks * 64 + cl) * 8;
    #pragma unroll
    for (int b = 0; b < NB; ++b) pp[b] = acc[b];
    __syncthreads();

    #pragma unroll
    for (int u = 0; u < 2; ++u) {
        const int idx = tid * 2 + u;               // 512 outputs per block
        const int c2 = idx >> 3, b = idx & 7;
        const int gcol = blockIdx.x * 64 + c2;
        float s = (part[(0 * 64 + c2) * 8 + b] + part[(1 * 64 + c2) * 8 + b])
                + (part[(2 * 64 + c2) * 8 + b] + part[(3 * 64 + c2) * 8 + b]);
        float t = rbf(s);
        t = rbf(t + rbf(bias[gcol]));
        if (MODE == 0) {
            t = rbf(30.0f * t);
            t = rbf(sinf(t));
        } else if (MODE == 1) {
            float r = rbf(in_s[b * K + gcol] + t);
            t = rbf(sinf(r));
        }
        outp[b * HID + gcol] = t;
    }
}

// ----------------- heads: 4-point groups, float4 loads, shfl-xor k-reduce ----------
// lane = ks*16 + pgl : pgl = point-group-in-wave (4 consecutive points each),
// ks = k-slice (lane bits 4..5). 256 blocks x 256 threads; 64 pgs per block.
__global__ __launch_bounds__(256) void k_heads(
    const float* __restrict__ h4,
    const float* __restrict__ wc, const float* __restrict__ bc,
    const float* __restrict__ wv, const float* __restrict__ bv,
    const float* __restrict__ coords0, const float* __restrict__ values0,
    float4* __restrict__ posval)
{
    __shared__ float hsT[HID * NB];              // [k][b], 8 KB, broadcast reads
    const int tid = threadIdx.x;
    for (int i = tid; i < NB * HID; i += 256) {
        int b = i >> 8, k = i & 255;
        hsT[k * 8 + b] = h4[b * HID + k];
    }
    __syncthreads();

    const int lane = tid & 63;
    const int wid  = tid >> 6;           // wave in block 0..3
    const int pgl  = lane & 15;
    const int ks   = lane >> 4;          // k-slice 0..3
    const int pg   = blockIdx.x * 64 + wid * 16 + pgl;   // global 4-point group

    float acc[4][4][8];                  // [point][x,y,z,val][batch] - 128 VGPRs
    #pragma unroll
    for (int p = 0; p < 4; ++p)
        #pragma unroll
        for (int c = 0; c < 4; ++c)
            #pragma unroll
            for (int b = 0; b < NB; ++b) acc[p][c][b] = 0.f;

    const float4* pwc = reinterpret_cast<const float4*>(wc + (size_t)(ks * 64) * (3 * NV)) + (size_t)pg * 3;
    const float4* pwv = reinterpret_cast<const float4*>(wv + (size_t)(ks * 64) * NV) + pg;
    const float4* phh = reinterpret_cast<const float4*>(hsT) + (ks * 64) * 2;

    #pragma unroll 2
    for (int i = 0; i < 64; ++i) {
        float4 wA = pwc[0], wB = pwc[1], wC = pwc[2];   // 48B: x0y0z0 x1y1z1 x2y2z2 x3y3z3
        float4 vv = pwv[0];
        float4 hA = phh[0], hB = phh[1];                 // h[k][b], wave-uniform broadcast
        float cx[4] = {wA.x, wA.w, wB.z, wC.y};
        float cy[4] = {wA.y, wB.x, wB.w, wC.z};
        float cz[4] = {wA.z, wB.y, wC.x, wC.w};
        float cv[4] = {vv.x, vv.y, vv.z, vv.w};
        float hb[8] = {hA.x, hA.y, hA.z, hA.w, hB.x, hB.y, hB.z, hB.w};
        #pragma unroll
        for (int p = 0; p < 4; ++p)
            #pragma unroll
            for (int b = 0; b < NB; ++b) {
                acc[p][0][b] = fmaf(hb[b], cx[p], acc[p][0][b]);
                acc[p][1][b] = fmaf(hb[b], cy[p], acc[p][1][b]);
                acc[p][2][b] = fmaf(hb[b], cz[p], acc[p][2][b]);
                acc[p][3][b] = fmaf(hb[b], cv[p], acc[p][3][b]);
            }
        pwc += 3 * NV / 4;
        pwv += NV / 4;
        phh += 2;
    }

    // cross-slice reduce: ks lives in lane bits 4..5 -> butterfly (s0+s1)+(s2+s3)
    #pragma unroll
    for (int p = 0; p < 4; ++p)
        #pragma unroll
        for (int c = 0; c < 4; ++c)
            #pragma unroll
            for (int b = 0; b < NB; ++b) {
                float t = acc[p][c][b];
                t += __shfl_xor(t, 16);
                t += __shfl_xor(t, 32);
                acc[p][c][b] = t;
            }

    // epilogue: all acc indices static; each lane stores batches {2ks, 2ks+1}
    const float factor = 0.5f * DD;
    float c0x[4], c0y[4], c0z[4], bcx[4], bcy[4], bcz[4], v0i[4], bvi[4];
    #pragma unroll
    for (int p = 0; p < 4; ++p) {
        const int vt = pg * 4 + p;
        c0x[p] = coords0[3 * vt]; c0y[p] = coords0[3 * vt + 1]; c0z[p] = coords0[3 * vt + 2];
        bcx[p] = bc[3 * vt];      bcy[p] = bc[3 * vt + 1];      bcz[p] = bc[3 * vt + 2];
        v0i[p] = values0[vt];     bvi[p] = bv[vt];
    }
    #pragma unroll
    for (int b = 0; b < NB; ++b) {
        #pragma unroll
        for (int p = 0; p < 4; ++p) {
            float px = factor * (c0x[p] + (acc[p][0][b] + bcx[p])) + factor;
            float py = factor * (c0y[p] + (acc[p][1][b] + bcy[p])) + factor;
            float pz = factor * (c0z[p] + (acc[p][2][b] + bcz[p])) + factor;
            float val = fmaxf(v0i[p] + (acc[p][3][b] + bvi[p]), 0.f);
            if ((b >> 1) == ks)
                posval[(size_t)b * NV + pg * 4 + p] = make_float4(px, py, pz, val);
        }
    }
}

// ----------------------------- binning helpers -------------------------------------
// brick(bx,by,bz) covers voxels x:[bx*32,+32) y:[by*8,+8) z:[bz*4,+4); bin=(bz*16+by)*4+bx
__device__ __forceinline__ bool point_base(float4 q, int& ix, int& iy, int& iz) {
    if (q.w == 0.f) return false;                   // relu-zeroed: no contribution
    ix = (int)floorf(q.x); iy = (int)floorf(q.y); iz = (int)floorf(q.z);
    return ix >= -1 && ix <= 127 && iy >= -1 && iy <= 127 && iz >= -1 && iz <= 127;
}

__device__ __forceinline__ void brick_span(int ix, int iy, int iz,
                                           int& bx0, int& bx1, int& by0, int& by1,
                                           int& bz0, int& bz1) {
    bx0 = (ix < 0 ? 0 : ix) >> 5;  bx1 = (ix + 1 > 127 ? 127 : ix + 1) >> 5;
    by0 = (iy < 0 ? 0 : iy) >> 3;  by1 = (iy + 1 > 127 ? 127 : iy + 1) >> 3;
    bz0 = (iz < 0 ? 0 : iz) >> 2;  bz1 = (iz + 1 > 127 ? 127 : iz + 1) >> 2;
}

// --------------- k_count: LDS histogram of (duplicated) entries per brick ----------
__global__ __launch_bounds__(256) void k_count(const float4* __restrict__ posval,
                                               unsigned* __restrict__ binCount)
{
    __shared__ unsigned hist[NBIN];   // 8 KB
    const int tid = threadIdx.x;
    const int batch = blockIdx.x >> 5;
    const size_t base = (size_t)batch * NV + (blockIdx.x & 31) * 2048;
    for (int i = tid; i < NBIN; i += 256) hist[i] = 0;
    __syncthreads();
    #pragma unroll
    for (int j = 0; j < 8; ++j) {
        float4 q = posval[base + j * 256 + tid];
        int ix, iy, iz;
        if (point_base(q, ix, iy, iz)) {
            int bx0, bx1, by0, by1, bz0, bz1;
            brick_span(ix, iy, iz, bx0, bx1, by0, by1, bz0, bz1);
            for (int bz = bz0; bz <= bz1; ++bz)
                for (int by = by0; by <= by1; ++by)
                    for (int bx = bx0; bx <= bx1; ++bx)
                        atomicAdd(&hist[(bz * 16 + by) * 4 + bx], 1u);
        }
    }
    __syncthreads();
    for (int i = tid; i < NBIN; i += 256) {
        unsigned c = hist[i];
        if (c) atomicAdd(&binCount[batch * NBIN + i], c);
    }
}

// --------------- k_scan: exclusive scan over 16384 bins (single block) -------------
__global__ __launch_bounds__(1024) void k_scan(const unsigned* __restrict__ cnt,
                                               unsigned* __restrict__ start,
                                               unsigned* __restrict__ cursor)
{
    __shared__ unsigned partial[1024];
    const int t = threadIdx.x;
    const int base = t * 16;
    unsigned s = 0;
    #pragma unroll
    for (int j = 0; j < 16; ++j) s += cnt[base + j];
    partial[t] = s;
    __syncthreads();
    for (int off = 1; off < 1024; off <<= 1) {
        unsigned mine = partial[t];
        unsigned add = (t >= off) ? partial[t - off] : 0u;
        __syncthreads();
        partial[t] = mine + add;
        __syncthreads();
    }
    unsigned run = (t > 0) ? partial[t - 1] : 0u;
    #pragma unroll
    for (int j = 0; j < 16; ++j) {
        start[base + j] = run;
        cursor[base + j] = run;
        run += cnt[base + j];
    }
    if (t == 1023) start[NBIN_TOT] = partial[1023];
}

// -------- k_scatter: copy each point into every touched brick's contiguous range ----
__global__ __launch_bounds__(256) void k_scatter(const float4* __restrict__ posval,
                                                 unsigned* __restrict__ binCursor,
                                                 float4* __restrict__ sorted)
{
    __shared__ unsigned hist[NBIN];    // counts, then reused as local cursor
    __shared__ unsigned bbase[NBIN];
    const int tid = threadIdx.x;
    const int batch = blockIdx.x >> 5;
    const size_t base = (size_t)batch * NV + (blockIdx.x & 31) * 2048;
    for (int i = tid; i < NBIN; i += 256) hist[i] = 0;
    __syncthreads();

    float4 q[8];
    #pragma unroll
    for (int j = 0; j < 8; ++j) {
        q[j] = posval[base + j * 256 + tid];
        int ix, iy, iz;
        if (point_base(q[j], ix, iy, iz)) {
            int bx0, bx1, by0, by1, bz0, bz1;
            brick_span(ix, iy, iz, bx0, bx1, by0, by1, bz0, bz1);
            for (int bz = bz0; bz <= bz1; ++bz)
                for (int by = by0; by <= by1; ++by)
                    for (int bx = bx0; bx <= bx1; ++bx)
                        atomicAdd(&hist[(bz * 16 + by) * 4 + bx], 1u);
        }
    }
    __syncthreads();
    for (int i = tid; i < NBIN; i += 256) {
        unsigned c = hist[i];
        bbase[i] = c ? atomicAdd(&binCursor[batch * NBIN + i], c) : 0u;
    }
    __syncthreads();
    for (int i = tid; i < NBIN; i += 256) hist[i] = 0;   // reuse as local cursor
    __syncthreads();
    #pragma unroll
    for (int j = 0; j < 8; ++j) {
        int ix, iy, iz;
        if (point_base(q[j], ix, iy, iz)) {
            int bx0, bx1, by0, by1, bz0, bz1;
            brick_span(ix, iy, iz, bx0, bx1, by0, by1, bz0, bz1);
            for (int bz = bz0; bz <= bz1; ++bz)
                for (int by = by0; by <= by1; ++by)
                    for (int bx = bx0; bx <= bx1; ++bx) {
                        int bin = (bz * 16 + by) * 4 + bx;
                        unsigned r = atomicAdd(&hist[bin], 1u);
                        sorted[bbase[bin] + r] = q[j];
                    }
        }
    }
}

// -------- k_binsplat: one block per 32x8x4 brick; exact list; LDS accumulate -------
__global__ __launch_bounds__(256) void k_binsplat(const float4* __restrict__ sorted,
                                                  const unsigned* __restrict__ binStart,
                                                  float* __restrict__ grid)
{
    __shared__ float brick[4 * 8 * 32];   // 4 KB
    const int tid = threadIdx.x;
    const int bid = blockIdx.x;           // [batch][bz 0..31][by 0..15][bx 0..3]
    const int bx = bid & 3;
    const int by = (bid >> 2) & 15;
    const int bz = (bid >> 6) & 31;
    const int batch = bid >> 11;
    const int x0 = bx << 5, y0 = by << 3, z0 = bz << 2;

    const unsigned s = binStart[bid], e = binStart[bid + 1];

    const int vx4 = tid & 7, cy = (tid >> 3) & 7, cz = tid >> 6;
    const size_t o = (size_t)batch * D3 + (size_t)(z0 + cz) * (DD * DD)
                   + (size_t)(y0 + cy) * DD + x0 + vx4 * 4;

    if (s == e) {   // empty brick: pure zero-write (replaces global memset)
        *reinterpret_cast<float4*>(grid + o) = make_float4(0.f, 0.f, 0.f, 0.f);
        return;
    }

    for (int i = tid; i < 1024; i += 256) brick[i] = 0.f;
    __syncthreads();

    for (unsigned i = s + tid; i < e; i += 256) {
        float4 q = sorted[i];
        float fx = floorf(q.x), fy = floorf(q.y), fz = floorf(q.z);
        int vx = (int)fx - x0, vy = (int)fy - y0, vz = (int)fz - z0;
        float gx = q.x - fx, gy = q.y - fy, gz = q.z - fz;
        float wx0 = 1.f - gx, wy0 = 1.f - gy, wz0 = 1.f - gz;
        #pragma unroll
        for (int oz = 0; oz < 2; ++oz)
        #pragma unroll
        for (int oy = 0; oy < 2; ++oy)
        #pragma unroll
        for (int ox = 0; ox < 2; ++ox) {
            int cxx = vx + ox, cyy = vy + oy, czz = vz + oz;
            if ((unsigned)cxx < 32u && (unsigned)cyy < 8u && (unsigned)czz < 4u) {
                float w = ((ox ? gx : wx0) * (oy ? gy : wy0)) * (oz ? gz : wz0);
                atomicAdd(&brick[(czz * 8 + cyy) * 32 + cxx], q.w * w);
            }
        }
    }
    __syncthreads();

    *reinterpret_cast<float4*>(grid + o) =
        *reinterpret_cast<const float4*>(&brick[(cz * 8 + cy) * 32 + vx4 * 4]);
}

// ------------------------- separable 7-tap gaussian blur (pencil) ------------------
__global__ __launch_bounds__(256) void k_blur(const float* __restrict__ in,
                                              float* __restrict__ out, int shift)
{
    const long i = (long)blockIdx.x * 256 + threadIdx.x;
    const int p = (int)((i >> shift) & (DD - 1));

    const double e1 = 0.6065306597126334, e2 = 0.1353352832366127, e3 = 0.011108996538242306;
    const double s = 1.0 + 2.0 * (e1 + e2 + e3);
    const float kw[7] = {(float)(e3 / s), (float)(e2 / s), (float)(e1 / s), (float)(1.0 / s),
                         (float)(e1 / s), (float)(e2 / s), (float)(e3 / s)};

    float acc = 0.f;
    #pragma unroll
    for (int j = -3; j <= 3; ++j) {
        int q = p + j;
        if (q >= 0 && q < DD)
            acc = fmaf(kw[j + 3], in[i + ((long)j << shift)], acc);
    }
    out[i] = acc;
}

// ------------------ fused y+x blur: 32-row y-strips per (batch, z) -----------------
__global__ __launch_bounds__(256) void k_blur_yx(const float* __restrict__ in,
                                                 float* __restrict__ out)
{
    __shared__ float sin_[38 * 128];   // 19 KB: 32 rows + 3 halo each side
    __shared__ float sy[32 * 128];     // 16 KB: y-blur result

    const double e1 = 0.6065306597126334, e2 = 0.1353352832366127, e3 = 0.011108996538242306;
    const double ss = 1.0 + 2.0 * (e1 + e2 + e3);
    const float kw[7] = {(float)(e3 / ss), (float)(e2 / ss), (float)(e1 / ss), (float)(1.0 / ss),
                         (float)(e1 / ss), (float)(e2 / ss), (float)(e3 / ss)};

    const int tid = threadIdx.x;
    const int bid = blockIdx.x;            // [batch][z][ytile]
    const int ytile = bid & 3;
    const int z = (bid >> 2) & 127;
    const int batch = bid >> 9;
    const int y0 = ytile << 5;
    const size_t slab = (size_t)batch * D3 + (size_t)z * (DD * DD);

    for (int i = tid; i < 38 * 128; i += 256) {
        int row = i >> 7, xx = i & 127;
        int gy = y0 + row - 3;
        sin_[i] = (gy >= 0 && gy < DD) ? in[slab + (size_t)gy * DD + xx] : 0.f;
    }
    __syncthreads();

    for (int i = tid; i < 32 * 128; i += 256) {
        int r = i >> 7, xx = i & 127;
        float acc = 0.f;
        #pragma unroll
        for (int j = 0; j < 7; ++j)
            acc = fmaf(kw[j], sin_[(r + j) * 128 + xx], acc);
        sy[i] = acc;
    }
    __syncthreads();

    for (int i = tid; i < 32 * 128; i += 256) {
        int r = i >> 7, xx = i & 127;
        float acc = 0.f;
        #pragma unroll
        for (int j = -3; j <= 3; ++j) {
            int qx = xx + j;
            if (qx >= 0 && qx < DD)
                acc = fmaf(kw[j + 3], sy[r * 128 + qx], acc);
        }
        out[slab + (size_t)(y0 + r) * DD + xx] = acc;
    }
}

extern "C" void kernel_launch(void* const* d_in, const int* in_sizes, int n_in,
                              void* d_out, int out_size, void* d_ws, size_t ws_size,
                              hipStream_t stream) {
    const float* x   = (const float*)d_in[0];
    const float* w0  = (const float*)d_in[1];
    const float* b0  = (const float*)d_in[2];
    const float* w1  = (const float*)d_in[3];
    const float* b1  = (const float*)d_in[4];
    const float* w2  = (const float*)d_in[5];
    const float* b2  = (const float*)d_in[6];
    const float* w3  = (const float*)d_in[7];
    const float* b3  = (const float*)d_in[8];
    const float* w4  = (const float*)d_in[9];
    const float* b4  = (const float*)d_in[10];
    const float* wc  = (const float*)d_in[11];
    const float* bc  = (const float*)d_in[12];
    const float* wv  = (const float*)d_in[13];
    const float* bv  = (const float*)d_in[14];
    const float* c0  = (const float*)d_in[15];
    const float* v0  = (const float*)d_in[16];

    float* out = (float*)d_out;
    // d_out staging (consumed before k_binsplat rewrites d_out as the raw grid):
    float4* posval = (float4*)d_out;                  // [NB][NV] float4 = 8 MiB
    float* h4 = out + 4 * 1024 * 1024;                // at +16 MiB
    float* hA = h4 + 2048;
    float* hB = hA + 2048;
    // ws staging (consumed before blur-z rewrites ws with the 64MB grid):
    float4* sorted = (float4*)d_ws;                   // ~6 MiB actual
    unsigned* binCount  = (unsigned*)((char*)d_ws + (48u << 20));
    unsigned* binStart  = binCount + NBIN_TOT;        // NBIN_TOT+1 entries
    unsigned* binCursor = binStart + NBIN_TOT + 1;

    hipMemsetAsync(binCount, 0, NBIN_TOT * sizeof(unsigned), stream);

    // SIREN MLP: 5 per-layer kernels, 4 blocks each
    k_layer<LAT, 0><<<4, 256, 0, stream>>>(x,  w0, b0, hA);
    k_layer<HID, 1><<<4, 256, 0, stream>>>(hA, w1, b1, hB);
    k_layer<HID, 1><<<4, 256, 0, stream>>>(hB, w2, b2, hA);
    k_layer<HID, 1><<<4, 256, 0, stream>>>(hA, w3, b3, hB);
    k_layer<HID, 2><<<4, 256, 0, stream>>>(hB, w4, b4, h4);

    k_heads<<<256, 256, 0, stream>>>(h4, wc, bc, wv, bv, c0, v0, posval);

    k_count<<<256, 256, 0, stream>>>(posval, binCount);
    k_scan<<<1, 1024, 0, stream>>>(binCount, binStart, binCursor);
    k_scatter<<<256, 256, 0, stream>>>(posval, binCursor, sorted);
    k_binsplat<<<NBIN_TOT, 256, 0, stream>>>(sorted, binStart, out);   // raw grid -> d_out

    const int nblk = (NB * D3) / 256;   // 65536
    k_blur<<<nblk, 256, 0, stream>>>(out, (float*)d_ws, 14);           // z: d_out -> ws
    k_blur_yx<<<NB * 512, 256, 0, stream>>>((float*)d_ws, out);        // y+x: ws -> d_out
}

// Round 8
// 362.347 us; speedup vs baseline: 1.0111x; 1.0111x over previous
//
#include <hip/hip_runtime.h>
#include <hip/hip_bf16.h>

#define DD 128
#define D3 (DD*DD*DD)      // 2097152
#define NB 8               // batch
#define NV 65536           // points
#define HID 256
#define LAT 128

// bricks: 32x8x4 voxels -> 4 x 16 x 32 = 2048 per batch, 16384 total
#define NBIN 2048
#define NBIN_TOT (NBIN*NB) // 16384

// round-to-nearest-even f32 -> bf16, returned as the (exactly representable) f32 value
__device__ __forceinline__ float rbf(float x) {
    unsigned u = __float_as_uint(x);
    unsigned r = (u + 0x7fffu + ((u >> 16) & 1u)) & 0xFFFF0000u;
    return __uint_as_float(r);
}

// ---------------- SIREN layer: one kernel per layer, 4 blocks x 256 threads --------
template<int K, int MODE>
__global__ __launch_bounds__(256) void k_layer(
    const float* __restrict__ in, const float* __restrict__ w,
    const float* __restrict__ bias, float* __restrict__ outp)
{
    __shared__ float in_s[NB * K];
    __shared__ float part[4 * 64 * 8];    // 8 KB
    const int tid = threadIdx.x;
    for (int i = tid; i < NB * K; i += 256) in_s[i] = rbf(in[i]);
    __syncthreads();

    const int cl = tid & 63;             // column within block (wave-contiguous)
    const int ks = tid >> 6;             // k-slice 0..3 (wave-uniform)
    const int col = blockIdx.x * 64 + cl;

    float acc[NB];
    #pragma unroll
    for (int b = 0; b < NB; ++b) acc[b] = 0.f;

    const int k0 = ks * (K / 4);
    #pragma unroll 8
    for (int k = k0; k < k0 + K / 4; ++k) {
        float wk = rbf(w[k * HID + col]);          // 256B/wave coalesced
        #pragma unroll
        for (int b = 0; b < NB; ++b) acc[b] = fmaf(in_s[b * K + k], wk, acc[b]);
    }

    float* pp = part + (ks * 64 + cl) * 8;
    #pragma unroll
    for (int b = 0; b < NB; ++b) pp[b] = acc[b];
    __syncthreads();

    #pragma unroll
    for (int u = 0; u < 2; ++u) {
        const int idx = tid * 2 + u;               // 512 outputs per block
        const int c2 = idx >> 3, b = idx & 7;
        const int gcol = blockIdx.x * 64 + c2;
        float s = (part[(0 * 64 + c2) * 8 + b] + part[(1 * 64 + c2) * 8 + b])
                + (part[(2 * 64 + c2) * 8 + b] + part[(3 * 64 + c2) * 8 + b]);
        float t = rbf(s);
        t = rbf(t + rbf(bias[gcol]));
        if (MODE == 0) {
            t = rbf(30.0f * t);
            t = rbf(sinf(t));
        } else if (MODE == 1) {
            float r = rbf(in_s[b * K + gcol] + t);
            t = rbf(sinf(r));
        }
        outp[b * HID + gcol] = t;
    }
}

// ------- heads: 2-point groups, 8-way K-split, float2 loads, shfl-xor reduce -------
// lane = ks*8 + pgl : pgl = 2-point group in wave (lane bits 0..2),
// ks = k-slice 0..7 (lane bits 3..5). 1024 blocks x 256 threads -> 16 waves/CU.
__global__ __launch_bounds__(256, 4) void k_heads(
    const float* __restrict__ h4,
    const float* __restrict__ wc, const float* __restrict__ bc,
    const float* __restrict__ wv, const float* __restrict__ bv,
    const float* __restrict__ coords0, const float* __restrict__ values0,
    float4* __restrict__ posval)
{
    // skewed [k][b] layout: addr(k,b) = k*8 + (k>>5)*4 + b  -> the 8 ks broadcast
    // groups hit disjoint 4-bank clusters on ds_read_b128 (conflict-free)
    __shared__ float hsT[HID * NB + 32];
    const int tid = threadIdx.x;
    for (int i = tid; i < NB * HID; i += 256) {
        int k = i >> 3, b = i & 7;
        hsT[k * 8 + (k >> 5) * 4 + b] = h4[b * HID + k];
    }
    __syncthreads();

    const int lane = tid & 63;
    const int wid  = tid >> 6;           // wave in block 0..3
    const int pgl  = lane & 7;
    const int ks   = lane >> 3;          // k-slice 0..7
    const int pg   = blockIdx.x * 32 + wid * 8 + pgl;   // global 2-point group

    float acc[2][4][8];                  // [point][x,y,z,val][batch] - 64 VGPRs
    #pragma unroll
    for (int p = 0; p < 2; ++p)
        #pragma unroll
        for (int c = 0; c < 4; ++c)
            #pragma unroll
            for (int b = 0; b < NB; ++b) acc[p][c][b] = 0.f;

    const float2* pwc = reinterpret_cast<const float2*>(wc) + (size_t)(ks * 32) * (3 * NV / 2) + (size_t)pg * 3;
    const float2* pwv = reinterpret_cast<const float2*>(wv) + (size_t)(ks * 32) * (NV / 2) + pg;
    const float4* phh = reinterpret_cast<const float4*>(hsT + (ks * 32) * 8 + ks * 4);

    #pragma unroll 2
    for (int i = 0; i < 32; ++i) {
        float2 wA = pwc[0], wB = pwc[1], wC = pwc[2];   // x0y0 | z0x1 | y1z1
        float2 vv = pwv[0];
        float4 hA = phh[0], hB = phh[1];                 // h[k][0..7], wave-broadcast
        float cx[2] = {wA.x, wB.y};
        float cy[2] = {wA.y, wC.x};
        float cz[2] = {wB.x, wC.y};
        float cv[2] = {vv.x, vv.y};
        float hb[8] = {hA.x, hA.y, hA.z, hA.w, hB.x, hB.y, hB.z, hB.w};
        #pragma unroll
        for (int p = 0; p < 2; ++p)
            #pragma unroll
            for (int b = 0; b < NB; ++b) {
                acc[p][0][b] = fmaf(hb[b], cx[p], acc[p][0][b]);
                acc[p][1][b] = fmaf(hb[b], cy[p], acc[p][1][b]);
                acc[p][2][b] = fmaf(hb[b], cz[p], acc[p][2][b]);
                acc[p][3][b] = fmaf(hb[b], cv[p], acc[p][3][b]);
            }
        pwc += 3 * NV / 2;
        pwv += NV / 2;
        phh += 2;
    }

    // cross-slice reduce: ks = lane bits 3..5 -> butterfly over masks 8,16,32
    #pragma unroll
    for (int p = 0; p < 2; ++p)
        #pragma unroll
        for (int c = 0; c < 4; ++c)
            #pragma unroll
            for (int b = 0; b < NB; ++b) {
                float t = acc[p][c][b];
                t += __shfl_xor(t, 8);
                t += __shfl_xor(t, 16);
                t += __shfl_xor(t, 32);
                acc[p][c][b] = t;
            }

    // lane handles batch b == ks; static select (no runtime acc indexing)
    float A[2][4];
    #pragma unroll
    for (int b = 0; b < NB; ++b)
        if (b == ks) {
            #pragma unroll
            for (int p = 0; p < 2; ++p) {
                A[p][0] = acc[p][0][b]; A[p][1] = acc[p][1][b];
                A[p][2] = acc[p][2][b]; A[p][3] = acc[p][3][b];
            }
        }

    const float factor = 0.5f * DD;
    #pragma unroll
    for (int p = 0; p < 2; ++p) {
        const int vt = pg * 2 + p;
        float px = factor * (coords0[3 * vt]     + (A[p][0] + bc[3 * vt]))     + factor;
        float py = factor * (coords0[3 * vt + 1] + (A[p][1] + bc[3 * vt + 1])) + factor;
        float pz = factor * (coords0[3 * vt + 2] + (A[p][2] + bc[3 * vt + 2])) + factor;
        float val = fmaxf(values0[vt] + (A[p][3] + bv[vt]), 0.f);
        posval[(size_t)ks * NV + vt] = make_float4(px, py, pz, val);
    }
}

// ----------------------------- binning helpers -------------------------------------
// brick(bx,by,bz) covers voxels x:[bx*32,+32) y:[by*8,+8) z:[bz*4,+4); bin=(bz*16+by)*4+bx
__device__ __forceinline__ bool point_base(float4 q, int& ix, int& iy, int& iz) {
    if (q.w == 0.f) return false;                   // relu-zeroed: no contribution
    ix = (int)floorf(q.x); iy = (int)floorf(q.y); iz = (int)floorf(q.z);
    return ix >= -1 && ix <= 127 && iy >= -1 && iy <= 127 && iz >= -1 && iz <= 127;
}

__device__ __forceinline__ void brick_span(int ix, int iy, int iz,
                                           int& bx0, int& bx1, int& by0, int& by1,
                                           int& bz0, int& bz1) {
    bx0 = (ix < 0 ? 0 : ix) >> 5;  bx1 = (ix + 1 > 127 ? 127 : ix + 1) >> 5;
    by0 = (iy < 0 ? 0 : iy) >> 3;  by1 = (iy + 1 > 127 ? 127 : iy + 1) >> 3;
    bz0 = (iz < 0 ? 0 : iz) >> 2;  bz1 = (iz + 1 > 127 ? 127 : iz + 1) >> 2;
}

// --------------- k_count: LDS histogram of (duplicated) entries per brick ----------
__global__ __launch_bounds__(256) void k_count(const float4* __restrict__ posval,
                                               unsigned* __restrict__ binCount)
{
    __shared__ unsigned hist[NBIN];   // 8 KB
    const int tid = threadIdx.x;
    const int batch = blockIdx.x >> 5;
    const size_t base = (size_t)batch * NV + (blockIdx.x & 31) * 2048;
    for (int i = tid; i < NBIN; i += 256) hist[i] = 0;
    __syncthreads();
    #pragma unroll
    for (int j = 0; j < 8; ++j) {
        float4 q = posval[base + j * 256 + tid];
        int ix, iy, iz;
        if (point_base(q, ix, iy, iz)) {
            int bx0, bx1, by0, by1, bz0, bz1;
            brick_span(ix, iy, iz, bx0, bx1, by0, by1, bz0, bz1);
            for (int bz = bz0; bz <= bz1; ++bz)
                for (int by = by0; by <= by1; ++by)
                    for (int bx = bx0; bx <= bx1; ++bx)
                        atomicAdd(&hist[(bz * 16 + by) * 4 + bx], 1u);
        }
    }
    __syncthreads();
    for (int i = tid; i < NBIN; i += 256) {
        unsigned c = hist[i];
        if (c) atomicAdd(&binCount[batch * NBIN + i], c);
    }
}

// --------------- k_scan: exclusive scan over 16384 bins (single block) -------------
__global__ __launch_bounds__(1024) void k_scan(const unsigned* __restrict__ cnt,
                                               unsigned* __restrict__ start,
                                               unsigned* __restrict__ cursor)
{
    __shared__ unsigned partial[1024];
    const int t = threadIdx.x;
    const int base = t * 16;
    unsigned s = 0;
    #pragma unroll
    for (int j = 0; j < 16; ++j) s += cnt[base + j];
    partial[t] = s;
    __syncthreads();
    for (int off = 1; off < 1024; off <<= 1) {
        unsigned mine = partial[t];
        unsigned add = (t >= off) ? partial[t - off] : 0u;
        __syncthreads();
        partial[t] = mine + add;
        __syncthreads();
    }
    unsigned run = (t > 0) ? partial[t - 1] : 0u;
    #pragma unroll
    for (int j = 0; j < 16; ++j) {
        start[base + j] = run;
        cursor[base + j] = run;
        run += cnt[base + j];
    }
    if (t == 1023) start[NBIN_TOT] = partial[1023];
}

// -------- k_scatter: copy each point into every touched brick's contiguous range ----
__global__ __launch_bounds__(256) void k_scatter(const float4* __restrict__ posval,
                                                 unsigned* __restrict__ binCursor,
                                                 float4* __restrict__ sorted)
{
    __shared__ unsigned hist[NBIN];    // counts, then reused as local cursor
    __shared__ unsigned bbase[NBIN];
    const int tid = threadIdx.x;
    const int batch = blockIdx.x >> 5;
    const size_t base = (size_t)batch * NV + (blockIdx.x & 31) * 2048;
    for (int i = tid; i < NBIN; i += 256) hist[i] = 0;
    __syncthreads();

    float4 q[8];
    #pragma unroll
    for (int j = 0; j < 8; ++j) {
        q[j] = posval[base + j * 256 + tid];
        int ix, iy, iz;
        if (point_base(q[j], ix, iy, iz)) {
            int bx0, bx1, by0, by1, bz0, bz1;
            brick_span(ix, iy, iz, bx0, bx1, by0, by1, bz0, bz1);
            for (int bz = bz0; bz <= bz1; ++bz)
                for (int by = by0; by <= by1; ++by)
                    for (int bx = bx0; bx <= bx1; ++bx)
                        atomicAdd(&hist[(bz * 16 + by) * 4 + bx], 1u);
        }
    }
    __syncthreads();
    for (int i = tid; i < NBIN; i += 256) {
        unsigned c = hist[i];
        bbase[i] = c ? atomicAdd(&binCursor[batch * NBIN + i], c) : 0u;
    }
    __syncthreads();
    for (int i = tid; i < NBIN; i += 256) hist[i] = 0;   // reuse as local cursor
    __syncthreads();
    #pragma unroll
    for (int j = 0; j < 8; ++j) {
        int ix, iy, iz;
        if (point_base(q[j], ix, iy, iz)) {
            int bx0, bx1, by0, by1, bz0, bz1;
            brick_span(ix, iy, iz, bx0, bx1, by0, by1, bz0, bz1);
            for (int bz = bz0; bz <= bz1; ++bz)
                for (int by = by0; by <= by1; ++by)
                    for (int bx = bx0; bx <= bx1; ++bx) {
                        int bin = (bz * 16 + by) * 4 + bx;
                        unsigned r = atomicAdd(&hist[bin], 1u);
                        sorted[bbase[bin] + r] = q[j];
                    }
        }
    }
}

// -------- k_binsplat: one block per 32x8x4 brick; exact list; LDS accumulate -------
__global__ __launch_bounds__(256) void k_binsplat(const float4* __restrict__ sorted,
                                                  const unsigned* __restrict__ binStart,
                                                  float* __restrict__ grid)
{
    __shared__ float brick[4 * 8 * 32];   // 4 KB
    const int tid = threadIdx.x;
    const int bid = blockIdx.x;           // [batch][bz 0..31][by 0..15][bx 0..3]
    const int bx = bid & 3;
    const int by = (bid >> 2) & 15;
    const int bz = (bid >> 6) & 31;
    const int batch = bid >> 11;
    const int x0 = bx << 5, y0 = by << 3, z0 = bz << 2;

    const unsigned s = binStart[bid], e = binStart[bid + 1];

    const int vx4 = tid & 7, cy = (tid >> 3) & 7, cz = tid >> 6;
    const size_t o = (size_t)batch * D3 + (size_t)(z0 + cz) * (DD * DD)
                   + (size_t)(y0 + cy) * DD + x0 + vx4 * 4;

    if (s == e) {   // empty brick: pure zero-write (replaces global memset)
        *reinterpret_cast<float4*>(grid + o) = make_float4(0.f, 0.f, 0.f, 0.f);
        return;
    }

    for (int i = tid; i < 1024; i += 256) brick[i] = 0.f;
    __syncthreads();

    for (unsigned i = s + tid; i < e; i += 256) {
        float4 q = sorted[i];
        float fx = floorf(q.x), fy = floorf(q.y), fz = floorf(q.z);
        int vx = (int)fx - x0, vy = (int)fy - y0, vz = (int)fz - z0;
        float gx = q.x - fx, gy = q.y - fy, gz = q.z - fz;
        float wx0 = 1.f - gx, wy0 = 1.f - gy, wz0 = 1.f - gz;
        #pragma unroll
        for (int oz = 0; oz < 2; ++oz)
        #pragma unroll
        for (int oy = 0; oy < 2; ++oy)
        #pragma unroll
        for (int ox = 0; ox < 2; ++ox) {
            int cxx = vx + ox, cyy = vy + oy, czz = vz + oz;
            if ((unsigned)cxx < 32u && (unsigned)cyy < 8u && (unsigned)czz < 4u) {
                float w = ((ox ? gx : wx0) * (oy ? gy : wy0)) * (oz ? gz : wz0);
                atomicAdd(&brick[(czz * 8 + cyy) * 32 + cxx], q.w * w);
            }
        }
    }
    __syncthreads();

    *reinterpret_cast<float4*>(grid + o) =
        *reinterpret_cast<const float4*>(&brick[(cz * 8 + cy) * 32 + vx4 * 4]);
}

// ------------------------- separable 7-tap gaussian blur (pencil) ------------------
__global__ __launch_bounds__(256) void k_blur(const float* __restrict__ in,
                                              float* __restrict__ out, int shift)
{
    const long i = (long)blockIdx.x * 256 + threadIdx.x;
    const int p = (int)((i >> shift) & (DD - 1));

    const double e1 = 0.6065306597126334, e2 = 0.1353352832366127, e3 = 0.011108996538242306;
    const double s = 1.0 + 2.0 * (e1 + e2 + e3);
    const float kw[7] = {(float)(e3 / s), (float)(e2 / s), (float)(e1 / s), (float)(1.0 / s),
                         (float)(e1 / s), (float)(e2 / s), (float)(e3 / s)};

    float acc = 0.f;
    #pragma unroll
    for (int j = -3; j <= 3; ++j) {
        int q = p + j;
        if (q >= 0 && q < DD)
            acc = fmaf(kw[j + 3], in[i + ((long)j << shift)], acc);
    }
    out[i] = acc;
}

// ------------------ fused y+x blur: 32-row y-strips per (batch, z) -----------------
__global__ __launch_bounds__(256) void k_blur_yx(const float* __restrict__ in,
                                                 float* __restrict__ out)
{
    __shared__ float sin_[38 * 128];   // 19 KB: 32 rows + 3 halo each side
    __shared__ float sy[32 * 128];     // 16 KB: y-blur result

    const double e1 = 0.6065306597126334, e2 = 0.1353352832366127, e3 = 0.011108996538242306;
    const double ss = 1.0 + 2.0 * (e1 + e2 + e3);
    const float kw[7] = {(float)(e3 / ss), (float)(e2 / ss), (float)(e1 / ss), (float)(1.0 / ss),
                         (float)(e1 / ss), (float)(e2 / ss), (float)(e3 / ss)};

    const int tid = threadIdx.x;
    const int bid = blockIdx.x;            // [batch][z][ytile]
    const int ytile = bid & 3;
    const int z = (bid >> 2) & 127;
    const int batch = bid >> 9;
    const int y0 = ytile << 5;
    const size_t slab = (size_t)batch * D3 + (size_t)z * (DD * DD);

    for (int i = tid; i < 38 * 128; i += 256) {
        int row = i >> 7, xx = i & 127;
        int gy = y0 + row - 3;
        sin_[i] = (gy >= 0 && gy < DD) ? in[slab + (size_t)gy * DD + xx] : 0.f;
    }
    __syncthreads();

    for (int i = tid; i < 32 * 128; i += 256) {
        int r = i >> 7, xx = i & 127;
        float acc = 0.f;
        #pragma unroll
        for (int j = 0; j < 7; ++j)
            acc = fmaf(kw[j], sin_[(r + j) * 128 + xx], acc);
        sy[i] = acc;
    }
    __syncthreads();

    for (int i = tid; i < 32 * 128; i += 256) {
        int r = i >> 7, xx = i & 127;
        float acc = 0.f;
        #pragma unroll
        for (int j = -3; j <= 3; ++j) {
            int qx = xx + j;
            if (qx >= 0 && qx < DD)
                acc = fmaf(kw[j + 3], sy[r * 128 + qx], acc);
        }
        out[slab + (size_t)(y0 + r) * DD + xx] = acc;
    }
}

extern "C" void kernel_launch(void* const* d_in, const int* in_sizes, int n_in,
                              void* d_out, int out_size, void* d_ws, size_t ws_size,
                              hipStream_t stream) {
    const float* x   = (const float*)d_in[0];
    const float* w0  = (const float*)d_in[1];
    const float* b0  = (const float*)d_in[2];
    const float* w1  = (const float*)d_in[3];
    const float* b1  = (const float*)d_in[4];
    const float* w2  = (const float*)d_in[5];
    const float* b2  = (const float*)d_in[6];
    const float* w3  = (const float*)d_in[7];
    const float* b3  = (const float*)d_in[8];
    const float* w4  = (const float*)d_in[9];
    const float* b4  = (const float*)d_in[10];
    const float* wc  = (const float*)d_in[11];
    const float* bc  = (const float*)d_in[12];
    const float* wv  = (const float*)d_in[13];
    const float* bv  = (const float*)d_in[14];
    const float* c0  = (const float*)d_in[15];
    const float* v0  = (const float*)d_in[16];

    float* out = (float*)d_out;
    // d_out staging (consumed before k_binsplat rewrites d_out as the raw grid):
    float4* posval = (float4*)d_out;                  // [NB][NV] float4 = 8 MiB
    float* h4 = out + 4 * 1024 * 1024;                // at +16 MiB
    float* hA = h4 + 2048;
    float* hB = hA + 2048;
    // ws staging (consumed before blur-z rewrites ws with the 64MB grid):
    float4* sorted = (float4*)d_ws;                   // ~6 MiB actual
    unsigned* binCount  = (unsigned*)((char*)d_ws + (48u << 20));
    unsigned* binStart  = binCount + NBIN_TOT;        // NBIN_TOT+1 entries
    unsigned* binCursor = binStart + NBIN_TOT + 1;

    hipMemsetAsync(binCount, 0, NBIN_TOT * sizeof(unsigned), stream);

    // SIREN MLP: 5 per-layer kernels, 4 blocks each
    k_layer<LAT, 0><<<4, 256, 0, stream>>>(x,  w0, b0, hA);
    k_layer<HID, 1><<<4, 256, 0, stream>>>(hA, w1, b1, hB);
    k_layer<HID, 1><<<4, 256, 0, stream>>>(hB, w2, b2, hA);
    k_layer<HID, 1><<<4, 256, 0, stream>>>(hA, w3, b3, hB);
    k_layer<HID, 2><<<4, 256, 0, stream>>>(hB, w4, b4, h4);

    k_heads<<<1024, 256, 0, stream>>>(h4, wc, bc, wv, bv, c0, v0, posval);

    k_count<<<256, 256, 0, stream>>>(posval, binCount);
    k_scan<<<1, 1024, 0, stream>>>(binCount, binStart, binCursor);
    k_scatter<<<256, 256, 0, stream>>>(posval, binCursor, sorted);
    k_binsplat<<<NBIN_TOT, 256, 0, stream>>>(sorted, binStart, out);   // raw grid -> d_out

    const int nblk = (NB * D3) / 256;   // 65536
    k_blur<<<nblk, 256, 0, stream>>>(out, (float*)d_ws, 14);           // z: d_out -> ws
    k_blur_yx<<<NB * 512, 256, 0, stream>>>((float*)d_ws, out);        // y+x: ws -> d_out
}